// Round 4
// baseline (501.989 us; speedup 1.0000x reference)
//
#include <hip/hip_runtime.h>
#include <hip/hip_bf16.h>
#include <stdint.h>

typedef __hip_bfloat16 bf16;
typedef __attribute__((ext_vector_type(8))) short short8;
typedef __attribute__((ext_vector_type(4))) float f32x4;

#define BM 128
#define BN 128

__device__ __forceinline__ unsigned short f2bf_bits(float x) {
    return __builtin_bit_cast(unsigned short, __float2bfloat16(x));
}

// async global->LDS, 16B per lane, LDS dest = wave-uniform base + lane*16
__device__ __forceinline__ void gload_lds16(const bf16* g, bf16* l) {
    __builtin_amdgcn_global_load_lds(
        (const __attribute__((address_space(1))) void*)(const void*)g,
        (__attribute__((address_space(3))) void*)(void*)l,
        16, 0, 0);
}

template <int N>
__device__ __forceinline__ void waitvm() {
    if constexpr (N == 0) asm volatile("s_waitcnt vmcnt(0)" ::: "memory");
    else if constexpr (N == 4) asm volatile("s_waitcnt vmcnt(4)" ::: "memory");
    else if constexpr (N == 6) asm volatile("s_waitcnt vmcnt(6)" ::: "memory");
}

// fused prep: [0,8192) feat->bf16 cvt; [8192,11264) W transpose+cvt; [11264] zero lsum
__global__ void prep_kernel(const float* __restrict__ feat, unsigned short* __restrict__ featb,
                            const float* __restrict__ W0, const float* __restrict__ W1,
                            const float* __restrict__ W2, bf16* __restrict__ Wt,
                            float* __restrict__ lsum) {
    const int b = blockIdx.x;
    const int tid = threadIdx.x;
    if (b < 8192) {
        int i = b * 256 + tid;
        float4 v = reinterpret_cast<const float4*>(feat)[i];
        ushort4 o;
        o.x = f2bf_bits(v.x); o.y = f2bf_bits(v.y);
        o.z = f2bf_bits(v.z); o.w = f2bf_bits(v.w);
        reinterpret_cast<ushort4*>(featb)[i] = o;
    } else if (b < 11264) {
        __shared__ float tile[32][33];
        const int b2 = b - 8192;
        const int z = b2 >> 10;
        const int t = b2 & 1023;
        const int bx = t & 31, by = t >> 5;
        const int tx = tid & 31, ty = tid >> 5;
        const float* in = (z == 0) ? W0 : (z == 1) ? W1 : W2;
        bf16* out = Wt + (size_t)z * 1024 * 1024;
        for (int r = ty; r < 32; r += 8)
            tile[r][tx] = in[(size_t)(by * 32 + r) * 1024 + bx * 32 + tx];
        __syncthreads();
        for (int r = ty; r < 32; r += 8)
            out[(size_t)(bx * 32 + r) * 1024 + by * 32 + tx] = __float2bfloat16(tile[tx][r]);
    } else {
        for (int i = tid; i < 8192; i += 256) lsum[i] = 0.f;
    }
}

__global__ void scale_rows(float* __restrict__ out, const float* __restrict__ lsum) {
    int i = blockIdx.x * 256 + threadIdx.x;
    float4 v = reinterpret_cast<float4*>(out)[i];
    float inv = 1.0f / lsum[i >> 8];
    v.x *= inv; v.y *= inv; v.z *= inv; v.w *= inv;
    reinterpret_cast<float4*>(out)[i] = v;
}

// ---------------------------------------------------------------------------
// gemm_bt: proven 128x128 2-barrier structure, 4 blocks/CU.
// Used for projections (MODE 0), PV (MODE 3), and the chunked fallback.
// ---------------------------------------------------------------------------
template <int MODE, int KH, int SWAP>
__global__ __launch_bounds__(256, 4)
void gemm_bt(const bf16* __restrict__ A, const bf16* __restrict__ B,
             const float* __restrict__ b0, const float* __restrict__ b1,
             const float* __restrict__ b2, float* __restrict__ lsum,
             bf16* __restrict__ outb, float* __restrict__ outf,
             int M, int N, int K, int ldb, int ldout, float scale) {
    constexpr int TILE = 128 * 32;
    constexpr int SELEMS = (2 * KH * TILE < 9216) ? 9216 : 2 * KH * TILE;
    __shared__ bf16 smem[SELEMS];
    bf16* As = smem;
    bf16* Bs = smem + KH * TILE;

    const int tid  = threadIdx.x;
    const int lane = tid & 63;
    const int wave = tid >> 6;
    const int wm = wave & 1, wn = wave >> 1;
    const int l16  = lane & 15;
    const int quad = lane >> 4;
    long bm0, bn0;
    if (SWAP == 2) {
        const int lin = blockIdx.y * 8 + blockIdx.x;
        const int xcd = lin & 7;
        const int s   = lin >> 3;
        bn0 = (long)(s & 7) * BN;
        bm0 = (long)((s >> 3) * 8 + xcd) * BM;
    } else {
        bm0 = (long)(SWAP ? blockIdx.y : blockIdx.x) * BM;
        bn0 = (long)(SWAP ? blockIdx.x : blockIdx.y) * BN;
    }

    const bf16* Ause = A;
    const bf16* Buse = B;
    bf16* oz = outb;
    int  ldo = ldout;
    int  z   = 0;
    if (MODE == 0) {
        z = blockIdx.z;
        if (z == 2) {
            bm0  = (long)blockIdx.y * BM;
            bn0  = (long)blockIdx.x * BN;
            Ause = B + (size_t)2 * N * K;
            Buse = A;
            oz   = outb + (size_t)2 * M * ldout;
            ldo  = M;
        } else {
            Buse = B + (size_t)z * N * K;
            oz   = outb + (size_t)z * M * ldout;
        }
    }

    const int lrow = lane >> 2;
    const int lcol = (lane & 3) * 8;
    const bf16* gA[2][KH];
    const bf16* gB[2][KH];
    bf16* lA[2][KH];
    bf16* lB[2][KH];
#pragma unroll
    for (int u = 0; u < 2; u++)
#pragma unroll
        for (int h = 0; h < KH; h++) {
            gA[u][h] = Ause + (size_t)(bm0 + wave * 32 + u * 16 + lrow) * K + h * 32 + lcol;
            gB[u][h] = Buse + (size_t)(bn0 + wave * 32 + u * 16 + lrow) * ldb + h * 32 + lcol;
            lA[u][h] = As + h * TILE + (wave * 32 + u * 16) * 32;
            lB[u][h] = Bs + h * TILE + (wave * 32 + u * 16) * 32;
        }

    const bf16* Ard = As + (wm * 64 + l16) * 32 + quad * 8;
    const bf16* Brd = Bs + (wn * 64 + l16) * 32 + quad * 8;

    f32x4 acc[4][4];
    const f32x4 zero = {0.f, 0.f, 0.f, 0.f};
#pragma unroll
    for (int i = 0; i < 4; i++)
#pragma unroll
        for (int j = 0; j < 4; j++) acc[i][j] = zero;

    for (int k0 = 0; k0 < K; k0 += KH * 32) {
        __syncthreads();
#pragma unroll
        for (int u = 0; u < 2; u++)
#pragma unroll
            for (int h = 0; h < KH; h++) {
                gload_lds16(gA[u][h] + k0, lA[u][h]);
                gload_lds16(gB[u][h] + k0, lB[u][h]);
            }
        __syncthreads();
#pragma unroll
        for (int h = 0; h < KH; h++) {
            short8 af[4], bfr[4];
#pragma unroll
            for (int mi = 0; mi < 4; mi++)
                af[mi] = *reinterpret_cast<const short8*>(Ard + h * TILE + mi * 16 * 32);
#pragma unroll
            for (int ni = 0; ni < 4; ni++)
                bfr[ni] = *reinterpret_cast<const short8*>(Brd + h * TILE + ni * 16 * 32);
#pragma unroll
            for (int mi = 0; mi < 4; mi++)
#pragma unroll
                for (int ni = 0; ni < 4; ni++)
                    acc[mi][ni] = __builtin_amdgcn_mfma_f32_16x16x32_bf16(af[mi], bfr[ni], acc[mi][ni], 0, 0, 0);
        }
    }

    if (MODE == 0 || MODE == 1) {
        __syncthreads();
        float bcol[4];
        if (MODE == 0 && z < 2) {
            const float* bias = (z == 0) ? b0 : b1;
#pragma unroll
            for (int ni = 0; ni < 4; ni++) bcol[ni] = bias[bn0 + wn * 64 + l16 + ni * 16];
        }
#pragma unroll
        for (int mi = 0; mi < 4; mi++) {
            bf16* eb = smem + ((wave << 1) | (mi & 1)) * 1152;
#pragma unroll
            for (int r = 0; r < 4; r++) {
                float s = 0.f;
                float brow = 0.f;
                if (MODE == 0 && z == 2) brow = b2[bm0 + wm * 64 + mi * 16 + quad * 4 + r];
#pragma unroll
                for (int ni = 0; ni < 4; ni++) {
                    float v = acc[mi][ni][r];
                    if (MODE == 0) v += (z == 2) ? brow : bcol[ni];
                    else { v = __expf(v * scale); s += v; }
                    eb[(quad * 4 + r) * 72 + ni * 16 + l16] = __float2bfloat16(v);
                }
                if (MODE == 1) {
                    s += __shfl_xor(s, 1);
                    s += __shfl_xor(s, 2);
                    s += __shfl_xor(s, 4);
                    s += __shfl_xor(s, 8);
                    if (l16 == 0) atomicAdd(&lsum[bm0 + wm * 64 + mi * 16 + quad * 4 + r], s);
                }
            }
            asm volatile("s_waitcnt lgkmcnt(0)" ::: "memory");
#pragma unroll
            for (int p = 0; p < 2; p++) {
                int r2 = p * 8 + (lane >> 3);
                int c2 = (lane & 7) * 8;
                short8 val = *reinterpret_cast<const short8*>(eb + r2 * 72 + c2);
                *reinterpret_cast<short8*>(
                    oz + (size_t)(bm0 + wm * 64 + mi * 16 + r2) * ldo + bn0 + wn * 64 + c2) = val;
            }
        }
    } else {
        const int rb2 = wm * 64 + quad * 4;
        const int cb2 = wn * 64 + l16;
#pragma unroll
        for (int mi = 0; mi < 4; mi++)
#pragma unroll
            for (int r = 0; r < 4; r++) {
                long row = bm0 + rb2 + mi * 16 + r;
                float mul = (MODE == 3) ? 1.0f / lsum[row] : 0.f;
#pragma unroll
                for (int ni = 0; ni < 4; ni++) {
                    long col = bn0 + cb2 + ni * 16;
                    if (MODE == 3) outf[row * ldout + col] = acc[mi][ni][r] * mul;
                    else           outf[row * ldout + col] += acc[mi][ni][r];
                }
            }
    }
}

// ---------------------------------------------------------------------------
// gemm8q: m201-faithful 8-phase QK^T + exp + row-sums.
// TM=TN=256, BK=64, 512 thr / 8 waves (2M x 4N), per-wave out 128x64.
// LDS 128 KiB: [dbuf2][mat2][half2][128x64] halves, st-swizzled
// (byte ^= (row&7)<<4; linear gload_lds dest + pre-swizzled global source +
//  swizzled ds_read — rule #21 both-sides involution).
// Phase cadence per K-tile u (4 phases, 16 MFMA each):
//   ph0: 12 ds_read (4 a-frags m{0,1} + all 8 b-frags, reg-carried) ; lgkm(8)
//   ph1-3: 4 ds_read (a-frags m{2r,2r+1})
// Stage-after-death: end-ph0: A1(u+1), B0(u+2); end-ph1: B1(u+2);
//   end-ph3: A0(u+2).  One counted vmcnt(4) at end-ph2 (2 loads x 2 younger
//   halves); ph3's barrier is the all-waves fence.  Never vmcnt(0) until tail.
// Prologue: T0 all + T1 {A0,B0,B1}, vmcnt(6).
// ---------------------------------------------------------------------------
__global__ __launch_bounds__(512, 1)
void gemm8q(const bf16* __restrict__ A, const bf16* __restrict__ B,
            float* __restrict__ lsum, bf16* __restrict__ outb,
            int K, int ldout, float scale) {
    // half-tile = 128 rows x 64 cols = 8192 elems (16 KiB); 8 slots = 128 KiB
    __shared__ __align__(16) bf16 smem[8 * 8192];

    const int tid  = threadIdx.x;
    const int lane = tid & 63;
    const int w    = tid >> 6;          // 0..7
    const int wm   = w >> 2;            // 0..1 row half of tile
    const int wn   = w & 3;             // 0..3 col quarter
    const int l16  = lane & 15;
    const int quad = lane >> 4;

    // bijective XCD swizzle: 1024 blocks, each XCD owns 128 contiguous slots
    const int bid = blockIdx.x;
    const int s   = (bid & 7) * 128 + (bid >> 3);
    const long bm0 = (long)(s >> 5) * 256;
    const long bn0 = (long)(s & 31) * 256;

    // ---- staging sources (pre-swizzled: col chunk (lane&7) XOR row&7) ----
    const int srow = lane >> 3;                    // row within 8-row stripe
    const int scol = ((lane & 7) ^ srow) * 8;      // swizzled col elem
    const bf16* gAs[2][2];  // [half][call]
    const bf16* gBs[2][2];
#pragma unroll
    for (int h = 0; h < 2; h++)
#pragma unroll
        for (int c = 0; c < 2; c++) {
            gAs[h][c] = A + (size_t)(bm0 + h * 128 + c * 64 + w * 8 + srow) * K + scol;
            gBs[h][c] = B + (size_t)(bn0 + h * 128 + c * 64 + w * 8 + srow) * K + scol;
        }
    // slot id = (dbuf<<2) | (mat<<1) | half ; mat: 0=A 1=B
    auto stg = [&](const bf16* const* src, int mh, int u) {
        bf16* base = smem + (size_t)((((u & 1) << 2) | mh) * 8192) + w * 512;
        gload_lds16(src[0] + (size_t)u * 64, base);
        gload_lds16(src[1] + (size_t)u * 64, base + 4096);
    };

    // ---- reader offsets (elements), with the same XOR swizzle ----
    const int swzb = (l16 & 7) << 4;   // byte XOR, constant per lane
    int colE[2];
#pragma unroll
    for (int ks = 0; ks < 2; ks++)
        colE[ks] = ((ks * 64 + quad * 16) ^ swzb) >> 1;
    const int arow = l16;                      // + mi*16, within half wm
    const int brow = (wn & 1) * 64 + l16;      // + ni*16, within half wn>>1
    const int slA = (0 << 1) | wm;             // A-half slot (sans dbuf)
    const int slB = (1 << 1) | (wn >> 1);

    const int T = K / 64;

    f32x4 acc[8][4];
    const f32x4 zero = {0.f, 0.f, 0.f, 0.f};
#pragma unroll
    for (int i = 0; i < 8; i++)
#pragma unroll
        for (int j = 0; j < 4; j++) acc[i][j] = zero;

    // ---- prologue: T0 {A0,A1,B0,B1} + T1 {A0,B0,B1}; wait oldest 8 ----
    stg(gAs[0], 0, 0); stg(gAs[1], 1, 0); stg(gBs[0], 2, 0); stg(gBs[1], 3, 0);
    stg(gAs[0], 0, 1); stg(gBs[0], 2, 1); stg(gBs[1], 3, 1);
    waitvm<6>();
    __builtin_amdgcn_s_barrier();

    for (int u = 0; u < T; ++u) {
        const bf16* sa = smem + (size_t)((((u & 1) << 2) | slA) * 8192);
        const bf16* sb = smem + (size_t)((((u & 1) << 2) | slB) * 8192);
        short8 bfr[2][4];
#pragma unroll
        for (int r = 0; r < 4; ++r) {
            short8 af[2][2];
            if (r == 0) {
#pragma unroll
                for (int ks = 0; ks < 2; ks++)
#pragma unroll
                    for (int ni = 0; ni < 4; ni++)
                        bfr[ks][ni] = *reinterpret_cast<const short8*>(
                            sb + (brow + ni * 16) * 64 + colE[ks]);
            }
#pragma unroll
            for (int j = 0; j < 2; j++)
#pragma unroll
                for (int ks = 0; ks < 2; ks++)
                    af[j][ks] = *reinterpret_cast<const short8*>(
                        sa + ((r * 2 + j) * 16 + arow) * 64 + colE[ks]);
            if (r == 0) asm volatile("s_waitcnt lgkmcnt(8)" ::: "memory");
            __builtin_amdgcn_s_barrier();
            asm volatile("s_waitcnt lgkmcnt(0)" ::: "memory");
            __builtin_amdgcn_sched_barrier(0);
            __builtin_amdgcn_s_setprio(1);
#pragma unroll
            for (int j = 0; j < 2; j++)
#pragma unroll
                for (int ks = 0; ks < 2; ks++)
#pragma unroll
                    for (int ni = 0; ni < 4; ni++)
                        acc[r * 2 + j][ni] = __builtin_amdgcn_mfma_f32_16x16x32_bf16(
                            af[j][ks], bfr[ks][ni], acc[r * 2 + j][ni], 0, 0, 0);
            __builtin_amdgcn_s_setprio(0);
            __builtin_amdgcn_s_barrier();
            // stage-after-death
            if (r == 0) {
                if (u + 1 < T) stg(gAs[1], 1, u + 1);   // A1(u) dies end-ph3(u-1)... A1(u+1) slot = A1(u-1): dead
                if (u + 2 < T) stg(gBs[0], 2, u + 2);   // B0(u) died end-ph0
            } else if (r == 1) {
                if (u + 2 < T) stg(gBs[1], 3, u + 2);   // B1(u) died end-ph0
            } else if (r == 2) {
                // counted wait: A1(u+1)'s 2 loads + all older done; leave
                // B0(u+2),B1(u+2) (4 loads) in flight.  ph3's barrier fences.
                if (u + 2 < T)      waitvm<4>();
                else if (u + 1 < T) waitvm<0>();
            } else {  // r == 3
                if (u + 2 < T) stg(gAs[0], 0, u + 2);   // A0(u) died end-ph3
            }
        }
    }
    __syncthreads();  // ring dead; reuse smem for epilogue staging

    // C/D layout (m89/m91): col = lane&15, row = quad*4 + r
#pragma unroll
    for (int mi = 0; mi < 8; mi++) {
        bf16* eb = smem + ((w << 1) | (mi & 1)) * 1152;
#pragma unroll
        for (int r = 0; r < 4; r++) {
            float ssum = 0.f;
#pragma unroll
            for (int ni = 0; ni < 4; ni++) {
                float v = __expf(acc[mi][ni][r] * scale);
                ssum += v;
                eb[(quad * 4 + r) * 72 + ni * 16 + l16] = __float2bfloat16(v);
            }
            ssum += __shfl_xor(ssum, 1);
            ssum += __shfl_xor(ssum, 2);
            ssum += __shfl_xor(ssum, 4);
            ssum += __shfl_xor(ssum, 8);
            if (l16 == 0)
                atomicAdd(&lsum[bm0 + wm * 128 + mi * 16 + quad * 4 + r], ssum);
        }
        asm volatile("s_waitcnt lgkmcnt(0)" ::: "memory");
#pragma unroll
        for (int p = 0; p < 2; p++) {
            int r2 = p * 8 + (lane >> 3);
            int c2 = (lane & 7) * 8;
            short8 val = *reinterpret_cast<const short8*>(eb + r2 * 72 + c2);
            *reinterpret_cast<short8*>(
                outb + (size_t)(bm0 + wm * 128 + mi * 16 + r2) * ldout + bn0 + wn * 64 + c2) = val;
        }
    }
}

extern "C" void kernel_launch(void* const* d_in, const int* in_sizes, int n_in,
                              void* d_out, int out_size, void* d_ws, size_t ws_size,
                              hipStream_t stream) {
    const float* feat = (const float*)d_in[0];
    const float* Wq   = (const float*)d_in[1];
    const float* bqv  = (const float*)d_in[2];
    const float* Wk   = (const float*)d_in[3];
    const float* bkv  = (const float*)d_in[4];
    const float* Wv   = (const float*)d_in[5];
    const float* bvv  = (const float*)d_in[6];
    float* outp = (float*)d_out;

    const int M = 8192, D = 1024;
    char* ws = (char*)d_ws;
    size_t off = 0;
    auto carve = [&](size_t bytes) -> char* {
        char* r = ws + off;
        off += (bytes + 255) & ~(size_t)255;
        return r;
    };
    bf16* featb = (bf16*)carve((size_t)M * D * 2);
    bf16* Wbt   = (bf16*)carve((size_t)3 * D * D * 2);
    bf16* qk    = (bf16*)carve((size_t)2 * M * D * 2 + (size_t)D * M * 2);
    bf16* vbt   = qk + (size_t)2 * M * D;
    float* lsum = (float*)carve((size_t)M * 4);
    size_t avail = (ws_size > off) ? ws_size - off : 0;

    int C;  // key-chunk width for P
    if      (avail >= (size_t)M * M * 2)    C = M;     // full P, 128 MB
    else if (avail >= (size_t)M * 4096 * 2) C = 4096;
    else if (avail >= (size_t)M * 2048 * 2) C = 2048;
    else                                    C = 1024;
    bf16* Pc = (bf16*)carve((size_t)M * C * 2);

    // 1) fused prep: feat->bf16, W transpose+cvt, lsum zero
    prep_kernel<<<dim3(11265), dim3(256), 0, stream>>>(
        feat, (unsigned short*)featb, Wq, Wk, Wv, Wbt, lsum);
    // 2) merged projection: z=0,1 -> q,k; z=2 -> v^T directly (BK=64)
    gemm_bt<0, 2, 0><<<dim3(M / 128, D / 128, 3), dim3(256), 0, stream>>>(
        featb, Wbt, bqv, bkv, bvv, nullptr, qk, nullptr, M, D, D, D, D, 1.0f);

    const float scale = 0.03125f;  // 1/sqrt(1024)
    bf16* qb = qk;
    bf16* kb = qk + (size_t)M * D;
    if (C == M) {
        // 3a) full P = exp(q k^T/32): m201-style 256^2 8-phase, 1024 blocks
        gemm8q<<<dim3(1024), dim3(512), 0, stream>>>(
            qb, kb, lsum, Pc, D, M, scale);
        // 4a) out = (P v^T)/lsum: proven 128x128, K=8192, XCD-swizzled grid
        gemm_bt<3, 2, 2><<<dim3(D / 128, M / 128), dim3(256), 0, stream>>>(
            Pc, vbt, nullptr, nullptr, nullptr, lsum, nullptr, outp, M, D, M, M, D, 0.f);
    } else {
        hipMemsetAsync(outp, 0, (size_t)M * D * 4, stream);
        for (int c = 0; c < M / C; c++) {
            gemm_bt<1, 2, 0><<<dim3(M / 128, C / 128), dim3(256), 0, stream>>>(
                qb, kb + (size_t)c * C * D, nullptr, nullptr, nullptr, lsum, Pc, nullptr,
                M, C, D, D, C, scale);
            gemm_bt<2, 2, 1><<<dim3(D / 128, M / 128), dim3(256), 0, stream>>>(
                Pc, vbt + (size_t)c * C, nullptr, nullptr, nullptr, nullptr, nullptr, outp,
                M, D, C, M, D, 0.f);
        }
        scale_rows<<<dim3(M * D / 4 / 256), dim3(256), 0, stream>>>(outp, lsum);
    }
}